// Round 2
// baseline (511.468 us; speedup 1.0000x reference)
//
#include <hip/hip_runtime.h>
#include <stdint.h>

// B=131072 rows, K=IN=256, N=OUT=256.
// temp = act @ weight.T (exact int32, |t| < 2^23); r = max|temp|;
// bw = ceil(log2(max(r,1))) (0 if r<=1); shift = bw-7;
// shift>0 ? round_shift(temp,shift) clipped to [-127,127] : int8-wrap(temp)
// exp_out = exp_in + weight_exp + max(shift,0)  (int16 semantics)
// Harness reads d_out as INT32: [B*N values, 1 exp scalar].
//
// v3: pass-1 rebuilt as barrier-free streaming GEMM.
//  - B (256x256 bf16 = 128 KB) staged in LDS ONCE per block (padded stride
//    264 -> ds_read_b128 at the conflict-free floor). 1 block/CU (132 KB LDS).
//  - 8 waves/block own disjoint 16-row strips; A goes global->regs directly
//    (16x128B coalesced segments), packed to bf16 via single v_perm.
//  - No __syncthreads in the main loop: waves stream independently ->
//    HBM-bound (~43 us floor for 134 MB read + 134 MB raw write).
// pass-2 unchanged: in-place elementwise quantize (raw temp LLC-resident).

#define M_ROWS 131072
#define NK 256
#define BLK_ROWS 512
#define BST 264      // padded LDS row stride (bf16 elems) = 528 B

typedef __attribute__((ext_vector_type(8))) short bf16x8;
typedef __attribute__((ext_vector_type(4))) float f32x4;
typedef __attribute__((ext_vector_type(4))) float fv4;
typedef __attribute__((ext_vector_type(4))) int iv4;
typedef __attribute__((ext_vector_type(4))) unsigned int u32x4;
typedef __attribute__((ext_vector_type(4))) unsigned short us4;

// bf16(lo) in low 16 bits, bf16(hi) in high 16 bits -- one v_perm_b32.
// exact for integer-valued floats |v| <= 255.
__device__ __forceinline__ uint32_t pack2(float lo, float hi) {
  return __builtin_amdgcn_perm(__float_as_uint(hi), __float_as_uint(lo),
                               0x07060302u);
}

// Prepass: weight fp32 -> bf16 (65536 elems; L2/LLC-resident, 128 KB).
// Also zero-inits gmax (replaces a separate memset dispatch).
__global__ void wconv(const float* __restrict__ w, unsigned short* __restrict__ wb,
                      int* __restrict__ gmax) {
  if (blockIdx.x == 0 && threadIdx.x == 0) *gmax = 0;
  const int i = blockIdx.x * 256 + threadIdx.x;
  const fv4 f = ((const fv4*)w)[i];
  us4 o;
  o.x = (unsigned short)(__float_as_uint(f.x) >> 16);
  o.y = (unsigned short)(__float_as_uint(f.y) >> 16);
  o.z = (unsigned short)(__float_as_uint(f.z) >> 16);
  o.w = (unsigned short)(__float_as_uint(f.w) >> 16);
  ((us4*)wb)[i] = o;
}

// pass 1: streaming GEMM -> raw int32 store + global abs-max.
__global__ __launch_bounds__(512, 2) void gemm_maxstore(
    const float* __restrict__ act, const unsigned short* __restrict__ wgtb,
    int* __restrict__ out, int* __restrict__ gmax)
{
  __shared__ __align__(16) short Bs[NK * BST];   // 132 KB -> 1 block/CU
  __shared__ int smax;
  const int tid = threadIdx.x;
  if (tid == 0) smax = 0;

  // Stage full B once: wb row-major [col][k] bf16 -> padded LDS.
  for (int v = tid; v < NK * NK / 8; v += 512) {
    const int col = v >> 5;           // 8 shorts per vec, 32 vecs per row
    const int k   = (v & 31) << 3;
    *(u32x4*)&Bs[col * BST + k] = ((const u32x4*)wgtb)[v];
  }
  __syncthreads();   // the only barrier before the epilogue

  const int lane = tid & 63;
  const int wave = tid >> 6;
  const int lm   = lane & 15;
  const int lk   = lane >> 4;
  const int bm   = blockIdx.x * BLK_ROWS;

  float fmaxv = 0.0f;

#pragma unroll 1
  for (int s = wave; s < BLK_ROWS / 16; s += 8) {   // 4 strips per wave
    const int row0 = bm + s * 16;
    const float* arow = act + (size_t)(row0 + lm) * NK;

    // Load the wave's full 16x256 A-strip: per lane 256 B (16 x dwordx4),
    // per instruction 16 rows x 128 B contiguous segments.
    fv4 araw[16];
#pragma unroll
    for (int kk = 0; kk < 8; ++kk) {
      araw[2 * kk]     = *(const fv4*)(arow + kk * 32 + lk * 8);
      araw[2 * kk + 1] = *(const fv4*)(arow + kk * 32 + lk * 8 + 4);
    }

    f32x4 acc[16] = {};
#pragma unroll
    for (int kk = 0; kk < 8; ++kk) {
      u32x4 apk;
      apk.x = pack2(araw[2 * kk].x,     araw[2 * kk].y);
      apk.y = pack2(araw[2 * kk].z,     araw[2 * kk].w);
      apk.z = pack2(araw[2 * kk + 1].x, araw[2 * kk + 1].y);
      apk.w = pack2(araw[2 * kk + 1].z, araw[2 * kk + 1].w);
      const bf16x8 af = __builtin_bit_cast(bf16x8, apk);
#pragma unroll
      for (int ni = 0; ni < 16; ++ni) {
        const bf16x8 bfr =
            *(const bf16x8*)&Bs[(ni * 16 + lm) * BST + kk * 32 + lk * 8];
        acc[ni] = __builtin_amdgcn_mfma_f32_16x16x32_bf16(af, bfr, acc[ni],
                                                          0, 0, 0);
      }
    }

    // Epilogue: abs-max + raw int32 store (cached -> LLC for pass 2).
    const size_t obase = (size_t)(row0 + lk * 4) * NK + lm;
#pragma unroll
    for (int ni = 0; ni < 16; ++ni)
#pragma unroll
      for (int r = 0; r < 4; ++r) {
        const float tv = acc[ni][r];
        fmaxv = fmaxf(fmaxv, fabsf(tv));
        out[obase + (size_t)r * NK + ni * 16] = (int)tv;
      }
  }

#pragma unroll
  for (int off = 32; off; off >>= 1)
    fmaxv = fmaxf(fmaxv, __shfl_xor(fmaxv, off, 64));
  if (lane == 0) atomicMax(&smax, (int)fmaxv);
  __syncthreads();
  if (tid == 0) atomicMax(gmax, smax);
}

// pass 2: in-place elementwise quantize of d_out (raw temp is LLC-hot).
__global__ __launch_bounds__(256) void quant_pass(
    int* __restrict__ out, const int* __restrict__ gmax,
    const int* __restrict__ exp_in, const int* __restrict__ wexp)
{
  const int rmax = *gmax;
  const int bw = (rmax <= 1) ? 0 : (32 - __clz(rmax - 1));   // ceil(log2(r))
  const int shift = bw - 7;
  const bool pos = shift > 0;
  const int s = shift < 1 ? 1 : shift;

  const size_t total  = (size_t)M_ROWS * NK / 4;  // int4 vectors
  const size_t stride = (size_t)gridDim.x * blockDim.x;
  for (size_t i = (size_t)blockIdx.x * blockDim.x + threadIdx.x; i < total;
       i += stride) {
    iv4 t = ((const iv4*)out)[i];
    iv4 q;
#pragma unroll
    for (int j = 0; j < 4; ++j) {
      const int ti = t[j];
      int r;
      if (pos) {
        const int rt = ti >> s;                       // floor(t / 2^s)
        const int dec = (ti - (rt << s)) >> (s - 1);  // {0,1}
        r = rt + dec;
        r = r > 127 ? 127 : (r < -127 ? -127 : r);
      } else {
        r = (int)(signed char)(ti & 0xFF);            // int8 wrap
      }
      q[j] = r;
    }
    __builtin_nontemporal_store(q, &((iv4*)out)[i]); // final, never re-read
  }

  if (blockIdx.x == 0 && threadIdx.x == 0) {
    const int e = exp_in[0] + wexp[0] + (pos ? shift : 0);
    out[(size_t)M_ROWS * NK] = (int)(short)e;
  }
}

extern "C" void kernel_launch(void* const* d_in, const int* in_sizes, int n_in,
                              void* d_out, int out_size, void* d_ws, size_t ws_size,
                              hipStream_t stream) {
  const float* act   = (const float*)d_in[0];
  const int* exp_in  = (const int*)d_in[1];
  const float* wgt   = (const float*)d_in[2];
  const int* wexp    = (const int*)d_in[3];
  int* gmax          = (int*)d_ws;
  unsigned short* wb = (unsigned short*)((char*)d_ws + 128);  // 128 KB bf16 weight

  wconv<<<dim3(64), dim3(256), 0, stream>>>(wgt, wb, gmax);
  gemm_maxstore<<<dim3(M_ROWS / BLK_ROWS), dim3(512), 0, stream>>>(
      act, wb, (int*)d_out, gmax);
  quant_pass<<<dim3(2048), dim3(256), 0, stream>>>((int*)d_out, gmax, exp_in, wexp);
}